// Round 16
// baseline (155.082 us; speedup 1.0000x reference)
//
#include <hip/hip_runtime.h>

#define NTH 64
#define B_TOTAL 32768
#define PSTR 20  // pstage row stride in floats (80B, 16B-aligned)

typedef float v2f __attribute__((ext_vector_type(2)));
typedef float v4f __attribute__((ext_vector_type(4)));
typedef double v4d __attribute__((ext_vector_type(4)));

struct Ptrs { const float* p[44]; };

enum : int {
  I_X = 0,
  I_WH0 = 1, I_WY0 = 2, I_WYU0 = 3, I_WU0 = 4,
  I_WH1 = 5, I_WZ1 = 6, I_WZU1 = 7, I_WY1 = 8, I_WYU1 = 9, I_WU1 = 10,
  I_WH2 = 11, I_WZ2 = 12, I_WZU2 = 13, I_WY2 = 14, I_WYU2 = 15, I_WU2 = 16,
  I_WZO = 17, I_WZUO = 18, I_WYO = 19, I_WYUO = 20, I_WUO = 21,
  I_BY0 = 22, I_BH0 = 23, I_B0 = 24, I_BH1 = 25, I_BY1 = 26, I_BZ1 = 27, I_B1 = 28,
  I_BH2 = 29, I_BZ2 = 30, I_BY2 = 31, I_B2 = 32, I_BZO = 33, I_BYO = 34, I_BOUT = 35,
  I_FC1 = 36, I_FC1B = 37, I_FC2 = 38, I_FC2B = 39, I_FC3 = 40, I_FC3B = 41,
  I_FC4 = 42, I_FC4B = 43
};

// contracted jet (16): c[0]=v, c[1..3]=dy, c[4..6]=dq,
// c[7..12]=d2yy sym {00,01,02,11,12,22}, c[13..15]=cyq[a] = sum_b y_b d2/dy_a dq_b
struct V16 { float c[16]; };

__device__ __forceinline__ float spf(float x) {
  return fmaxf(x, 0.0f) + __logf(1.0f + __expf(-fabsf(x)));
}
__device__ __forceinline__ float sigf(float x) {
  return __fdividef(1.0f, 1.0f + __expf(-x));
}

__device__ __forceinline__ V16 spchain16(const V16& A, float y0, float y1, float y2) {
  V16 Z;
  float s = sigf(A.c[0]);
  float d = s * (1.0f - s);
  Z.c[0] = spf(A.c[0]);
#pragma unroll
  for (int a = 0; a < 3; ++a) Z.c[1 + a] = s * A.c[1 + a];
#pragma unroll
  for (int b = 0; b < 3; ++b) Z.c[4 + b] = s * A.c[4 + b];
  Z.c[7]  = s * A.c[7]  + d * A.c[1] * A.c[1];
  Z.c[8]  = s * A.c[8]  + d * A.c[1] * A.c[2];
  Z.c[9]  = s * A.c[9]  + d * A.c[1] * A.c[3];
  Z.c[10] = s * A.c[10] + d * A.c[2] * A.c[2];
  Z.c[11] = s * A.c[11] + d * A.c[2] * A.c[3];
  Z.c[12] = s * A.c[12] + d * A.c[3] * A.c[3];
  float ydq = y0 * A.c[4] + y1 * A.c[5] + y2 * A.c[6];
#pragma unroll
  for (int a = 0; a < 3; ++a) Z.c[13 + a] = s * A.c[13 + a] + d * A.c[1 + a] * ydq;
  return Z;
}

// P = Z * S (product rule, contracted), streamed to LDS row (stride PSTR floats)
__device__ __forceinline__ void stageProd(float* row, const V16& Z, float S0, float S1,
                                          float S2, float S3, float y0, float y1, float y2) {
  float z0 = Z.c[0];
  float ysd = y0 * S1 + y1 * S2 + y2 * S3;
  v4f w0 = {z0 * S0, S0 * Z.c[1], S0 * Z.c[2], S0 * Z.c[3]};
  v4f w1 = {z0 * S1 + S0 * Z.c[4], z0 * S2 + S0 * Z.c[5], z0 * S3 + S0 * Z.c[6], S0 * Z.c[7]};
  v4f w2 = {S0 * Z.c[8], S0 * Z.c[9], S0 * Z.c[10], S0 * Z.c[11]};
  v4f w3 = {S0 * Z.c[12], S0 * Z.c[13] + Z.c[1] * ysd, S0 * Z.c[14] + Z.c[2] * ysd,
            S0 * Z.c[15] + Z.c[3] * ysd};
  *(v4f*)(row + 0) = w0;  *(v4f*)(row + 4) = w1;
  *(v4f*)(row + 8) = w2;  *(v4f*)(row + 12) = w3;
}

__device__ __forceinline__ V16 prodZS16(const V16& Z, float S0, float S1, float S2, float S3,
                                        float y0, float y1, float y2) {
  V16 P;
  const float Sq[3] = {S1, S2, S3};
  float ysd = y0 * S1 + y1 * S2 + y2 * S3;
  P.c[0] = Z.c[0] * S0;
#pragma unroll
  for (int a = 0; a < 3; ++a) P.c[1 + a] = S0 * Z.c[1 + a];
#pragma unroll
  for (int b = 0; b < 3; ++b) P.c[4 + b] = Z.c[0] * Sq[b] + S0 * Z.c[4 + b];
#pragma unroll
  for (int t = 0; t < 6; ++t) P.c[7 + t] = S0 * Z.c[7 + t];
#pragma unroll
  for (int a = 0; a < 3; ++a) P.c[13 + a] = S0 * Z.c[13 + a] + Z.c[1 + a] * ysd;
  return P;
}

// fused u-consumer (VALU)
__device__ __forceinline__ void stageU_all(const float* __restrict__ Wh,
                                           const float* __restrict__ Wzu,
                                           const float* __restrict__ Wu,
                                           const float* __restrict__ Wyu, int j,
                                           const float* us,
                                           v2f& h0, v2f& h1, v2f& s0, v2f& s1,
                                           v2f& w0, v2f& w1,
                                           v2f& ta0, v2f& ta1, v2f& tb0, v2f& tb1,
                                           v2f& tc0, v2f& tc1) {
#pragma unroll 2
  for (int i = 0; i < 32; ++i) {
    v4f u = *(const v4f*)(us + i * 4);
    float wh = Wh[i * 32 + j], wz = Wzu[i * 32 + j], wu = Wu[i * 32 + j];
    h0 += u.xy * wh; h1 += u.zw * wh;
    s0 += u.xy * wz; s1 += u.zw * wz;
    w0 += u.xy * wu; w1 += u.zw * wu;
    float wy0 = Wyu[i * 3 + 0], wy1 = Wyu[i * 3 + 1], wy2 = Wyu[i * 3 + 2];
    ta0 += u.xy * wy0; ta1 += u.zw * wy0;
    tb0 += u.xy * wy1; tb1 += u.zw * wy1;
    tc0 += u.xy * wy2; tc1 += u.zw * wy2;
  }
}

// local pre-activation terms, contracted: A = w + (y*t)@Wy
__device__ __forceinline__ void buildA16(const float* __restrict__ Wy, int j, float y0, float y1,
                                         float y2, const float wv[4], const float ta[4],
                                         const float tb[4], const float tc[4], V16& A) {
  float wy0 = Wy[j], wy1 = Wy[32 + j], wy2 = Wy[64 + j];
  A.c[0] = wv[0] + y0 * ta[0] * wy0 + y1 * tb[0] * wy1 + y2 * tc[0] * wy2;
  A.c[1] = ta[0] * wy0; A.c[2] = tb[0] * wy1; A.c[3] = tc[0] * wy2;
#pragma unroll
  for (int b = 0; b < 3; ++b)
    A.c[4 + b] = wv[1 + b] + y0 * ta[1 + b] * wy0 + y1 * tb[1 + b] * wy1 + y2 * tc[1 + b] * wy2;
#pragma unroll
  for (int t6 = 0; t6 < 6; ++t6) A.c[7 + t6] = 0.0f;
  float yta = y0 * ta[1] + y1 * ta[2] + y2 * ta[3];
  float ytb = y0 * tb[1] + y1 * tb[2] + y2 * tb[3];
  float ytc = y0 * tc[1] + y1 * tc[2] + y2 * tc[3];
  A.c[13] = yta * wy0; A.c[14] = ytb * wy1; A.c[15] = ytc * wy2;
}

// V chain (VALU, serial); returns dV/dq via refs
__device__ __forceinline__ void vchainVALU(const Ptrs& P, int j, float q0, float q1, float q2,
                                           float* urow, float& Vg0, float& Vg1, float& Vg2) {
  const float* fc1 = P.p[I_FC1];
  float f0 = fc1[j * 3], f1 = fc1[j * 3 + 1], f2 = fc1[j * 3 + 2];
  float hp = P.p[I_FC1B][j] + q0 * f0 + q1 * f1 + q2 * f2;
  float ss = sigf(hp);
  *(v4f*)(urow + j * 4) = (v4f){spf(hp), ss * f0, ss * f1, ss * f2};
  const float* fc2 = P.p[I_FC2] + j * 32;
  v2f a0 = {P.p[I_FC2B][j], 0.0f}, a1 = {0.0f, 0.0f};
#pragma unroll 2
  for (int r = 0; r < 8; ++r) {
    v4f w4 = *(const v4f*)(fc2 + r * 4);
    v4f u0 = *(const v4f*)(urow + (r * 4 + 0) * 4);
    v4f u1 = *(const v4f*)(urow + (r * 4 + 1) * 4);
    v4f u2 = *(const v4f*)(urow + (r * 4 + 2) * 4);
    v4f u3 = *(const v4f*)(urow + (r * 4 + 3) * 4);
    a0 += u0.xy * w4.x; a1 += u0.zw * w4.x;
    a0 += u1.xy * w4.y; a1 += u1.zw * w4.y;
    a0 += u2.xy * w4.z; a1 += u2.zw * w4.z;
    a0 += u3.xy * w4.w; a1 += u3.zw * w4.w;
  }
  float ss2 = sigf(a0.x);
  *(v4f*)(urow + j * 4) = (v4f){spf(a0.x), ss2 * a0.y, ss2 * a1.x, ss2 * a1.y};
  const float* fc3 = P.p[I_FC3] + j * 32;
  v2f b0 = {P.p[I_FC3B][j], 0.0f}, b1 = {0.0f, 0.0f};
#pragma unroll 2
  for (int r = 0; r < 8; ++r) {
    v4f w4 = *(const v4f*)(fc3 + r * 4);
    v4f u0 = *(const v4f*)(urow + (r * 4 + 0) * 4);
    v4f u1 = *(const v4f*)(urow + (r * 4 + 1) * 4);
    v4f u2 = *(const v4f*)(urow + (r * 4 + 2) * 4);
    v4f u3 = *(const v4f*)(urow + (r * 4 + 3) * 4);
    b0 += u0.xy * w4.x; b1 += u0.zw * w4.x;
    b0 += u1.xy * w4.y; b1 += u1.zw * w4.y;
    b0 += u2.xy * w4.z; b1 += u2.zw * w4.z;
    b0 += u3.xy * w4.w; b1 += u3.zw * w4.w;
  }
  float ss3 = sigf(b0.x);
  float f4 = P.p[I_FC4][j];
  Vg0 = ss3 * b0.y * f4; Vg1 = ss3 * b1.x * f4; Vg2 = ss3 * b1.y * f4;
}

// z1 init (VALU)
__device__ __forceinline__ V16 zinit(const Ptrs& P, int j, float q0, float q1, float q2,
                                     float y0, float y1, float y2) {
  const float* yu0 = P.p[I_WYU0];
  float t0v[3];
#pragma unroll
  for (int k = 0; k < 3; ++k)
    t0v[k] = q0 * yu0[k] + q1 * yu0[3 + k] + q2 * yu0[6 + k] + P.p[I_BY0][k];
  const float* Wy = P.p[I_WY0];
  const float* Wu = P.p[I_WU0];
  float wy0 = Wy[j], wy1 = Wy[32 + j], wy2 = Wy[64 + j];
  float wu0 = Wu[j], wu1 = Wu[32 + j], wu2 = Wu[64 + j];
  V16 A;
  A.c[0] = P.p[I_B0][j] + (y0 * t0v[0]) * wy0 + (y1 * t0v[1]) * wy1 + (y2 * t0v[2]) * wy2 +
           q0 * wu0 + q1 * wu1 + q2 * wu2;
  A.c[1] = t0v[0] * wy0; A.c[2] = t0v[1] * wy1; A.c[3] = t0v[2] * wy2;
#pragma unroll
  for (int b = 0; b < 3; ++b) {
    float acc = (b == 0 ? wu0 : (b == 1 ? wu1 : wu2));
    acc += y0 * yu0[b * 3 + 0] * wy0 + y1 * yu0[b * 3 + 1] * wy1 + y2 * yu0[b * 3 + 2] * wy2;
    A.c[4 + b] = acc;
  }
#pragma unroll
  for (int t = 0; t < 6; ++t) A.c[7 + t] = 0.0f;
  float yty0 = y0 * yu0[0] + y1 * yu0[3] + y2 * yu0[6];
  float yty1 = y0 * yu0[1] + y1 * yu0[4] + y2 * yu0[7];
  float yty2 = y0 * yu0[2] + y1 * yu0[5] + y2 * yu0[8];
  A.c[13] = yty0 * wy0; A.c[14] = yty1 * wy1; A.c[15] = yty2 * wy2;
  return spchain16(A, y0, y1, y2);
}

// u1 init (VALU)
__device__ __forceinline__ void u1init(const Ptrs& P, int j, float q0, float q1, float q2,
                                       float u1c[4]) {
  const float* wh0 = P.p[I_WH0];
  float w0 = wh0[j], w1 = wh0[32 + j], w2 = wh0[64 + j];
  float h = P.p[I_BH0][j] + q0 * w0 + q1 * w1 + q2 * w2;
  float ss = sigf(h);
  u1c[0] = spf(h); u1c[1] = ss * w0; u1c[2] = ss * w1; u1c[3] = ss * w2;
}

// mv16 MFMA over two sample buffers (f64 16x16x4, layouts verified R11)
__device__ __forceinline__ void mv16pair(const float* __restrict__ Wz, int n16, int kq,
                                         float* pstX, float* pstY) {
  v4d a00 = {0.0, 0.0, 0.0, 0.0};
  v4d a01 = {0.0, 0.0, 0.0, 0.0};
  v4d a10 = {0.0, 0.0, 0.0, 0.0};
  v4d a11 = {0.0, 0.0, 0.0, 0.0};
#pragma unroll
  for (int c = 0; c < 8; ++c) {
    const int i = c * 4 + kq;
    double b0 = (double)pstX[i * PSTR + n16];
    double b1 = (double)pstY[i * PSTR + n16];
    double wlo = (double)fmaxf(Wz[i * 32 + n16], 0.0f);
    double whi = (double)fmaxf(Wz[i * 32 + 16 + n16], 0.0f);
    a00 = __builtin_amdgcn_mfma_f64_16x16x4f64(wlo, b0, a00, 0, 0, 0);
    a01 = __builtin_amdgcn_mfma_f64_16x16x4f64(whi, b0, a01, 0, 0, 0);
    a10 = __builtin_amdgcn_mfma_f64_16x16x4f64(wlo, b1, a10, 0, 0, 0);
    a11 = __builtin_amdgcn_mfma_f64_16x16x4f64(whi, b1, a11, 0, 0, 0);
  }
#pragma unroll
  for (int r = 0; r < 4; ++r) {
    pstX[(kq + 4 * r) * PSTR + n16]      = (float)a00[r];
    pstX[(16 + kq + 4 * r) * PSTR + n16] = (float)a01[r];
    pstY[(kq + 4 * r) * PSTR + n16]      = (float)a10[r];
    pstY[(16 + kq + 4 * r) * PSTR + n16] = (float)a11[r];
  }
}

// level-3 (VALU, fused single pass)
__device__ __forceinline__ void level3VALU(const Ptrs& P, int j, const float* urow,
                                           float s3c[4], float t3av[4], float t3bv[4],
                                           float t3cv[4], float woc[4]) {
  v2f s30 = {P.p[I_BZO][j], 0.0f}, s31 = {0.0f, 0.0f};
  v2f wo0 = {0.0f, 0.0f}, wo1 = {0.0f, 0.0f};
  v2f t3a0 = {P.p[I_BYO][0], 0.0f}, t3a1 = {0.0f, 0.0f};
  v2f t3b0 = {P.p[I_BYO][1], 0.0f}, t3b1 = {0.0f, 0.0f};
  v2f t3c0 = {P.p[I_BYO][2], 0.0f}, t3c1 = {0.0f, 0.0f};
  const float* Wzuo = P.p[I_WZUO];
  const float* Wuo = P.p[I_WUO];
  const float* Wyuo = P.p[I_WYUO];
#pragma unroll 2
  for (int i = 0; i < 32; ++i) {
    v4f u = *(const v4f*)(urow + i * 4);
    float wz = Wzuo[i * 32 + j];
    s30 += u.xy * wz; s31 += u.zw * wz;
    float wu = Wuo[i];
    wo0 += u.xy * wu; wo1 += u.zw * wu;
    float wy0 = Wyuo[i * 3], wy1 = Wyuo[i * 3 + 1], wy2 = Wyuo[i * 3 + 2];
    t3a0 += u.xy * wy0; t3a1 += u.zw * wy0;
    t3b0 += u.xy * wy1; t3b1 += u.zw * wy1;
    t3c0 += u.xy * wy2; t3c1 += u.zw * wy2;
  }
  s3c[0] = s30.x; s3c[1] = s30.y; s3c[2] = s31.x; s3c[3] = s31.y;
  woc[0] = wo0.x; woc[1] = wo0.y; woc[2] = wo1.x; woc[3] = wo1.y;
  t3av[0] = t3a0.x; t3av[1] = t3a0.y; t3av[2] = t3a1.x; t3av[3] = t3a1.y;
  t3bv[0] = t3b0.x; t3bv[1] = t3b0.y; t3bv[2] = t3b1.x; t3bv[3] = t3b1.y;
  t3cv[0] = t3c0.x; t3cv[1] = t3c0.y; t3cv[2] = t3c1.x; t3cv[3] = t3c1.y;
}

// reduce + 3x3 solve + store (j==0 lanes)
__device__ __forceinline__ void finishSample(const Ptrs& P, int j, const V16& z,
                                             const float s3c[4], const float t3av[4],
                                             const float t3bv[4], const float t3cv[4],
                                             const float woc[4], float Vg0, float Vg1, float Vg2,
                                             float q0, float q1, float q2, float y0, float y1,
                                             float y2, float* __restrict__ out, int sample) {
  float red[19];
  {
    V16 p3 = prodZS16(z, s3c[0], s3c[1], s3c[2], s3c[3], y0, y1, y2);
    float wz = fmaxf(P.p[I_WZO][j], 0.0f);
#pragma unroll
    for (int k = 0; k < 16; ++k) red[k] = p3.c[k] * wz;
    red[16] = Vg0; red[17] = Vg1; red[18] = Vg2;
  }
#pragma unroll
  for (int m = 16; m >= 1; m >>= 1) {
#pragma unroll
    for (int k = 0; k < 19; ++k) red[k] += __shfl_xor(red[k], m, 32);
  }
  if (j == 0) {
    const float* Wyo = P.p[I_WYO];
    const float wyo0 = Wyo[0], wyo1 = Wyo[1], wyo2 = Wyo[2];
    float Av = red[0] + woc[0] + P.p[I_BOUT][0] + y0 * t3av[0] * wyo0 +
               y1 * t3bv[0] * wyo1 + y2 * t3cv[0] * wyo2;
    float Agy[3];
    Agy[0] = red[1] + t3av[0] * wyo0;
    Agy[1] = red[2] + t3bv[0] * wyo1;
    Agy[2] = red[3] + t3cv[0] * wyo2;
    float Agq[3];
#pragma unroll
    for (int b = 0; b < 3; ++b)
      Agq[b] = red[4 + b] + woc[1 + b] + y0 * t3av[1 + b] * wyo0 +
               y1 * t3bv[1 + b] * wyo1 + y2 * t3cv[1 + b] * wyo2;
    float ycq[3];
    ycq[0] = red[13] + (y0 * t3av[1] + y1 * t3av[2] + y2 * t3av[3]) * wyo0;
    ycq[1] = red[14] + (y0 * t3bv[1] + y1 * t3bv[2] + y2 * t3bv[3]) * wyo1;
    ycq[2] = red[15] + (y0 * t3cv[1] + y1 * t3cv[2] + y2 * t3cv[3]) * wyo2;
    float s = sigf(Av), d = s * (1.0f - s);
    double Mm[3][3];
    const int pa[6] = {0, 0, 0, 1, 1, 2}, pb[6] = {0, 1, 2, 1, 2, 2};
#pragma unroll
    for (int t = 0; t < 6; ++t) {
      double m = (double)s * (double)red[7 + t] +
                 (double)d * (double)Agy[pa[t]] * (double)Agy[pb[t]];
      Mm[pa[t]][pb[t]] = m; Mm[pb[t]][pa[t]] = m;
    }
    double yAgq = (double)y0 * (double)Agq[0] + (double)y1 * (double)Agq[1] +
                  (double)y2 * (double)Agq[2];
    double rr[3];
#pragma unroll
    for (int a = 0; a < 3; ++a) {
      double g = (double)s * (double)Agq[a] - (double)red[16 + a];
      double Cy = (double)s * (double)ycq[a] + (double)d * (double)Agy[a] * yAgq;
      rr[a] = g - Cy;
    }
    double a = Mm[0][0], b_ = Mm[0][1], c_ = Mm[0][2], dd = Mm[1][1], e = Mm[1][2], f = Mm[2][2];
    double A00 = dd * f - e * e, A01 = c_ * e - b_ * f, A02 = b_ * e - c_ * dd;
    double A11 = a * f - c_ * c_, A12 = b_ * c_ - a * e, A22 = a * dd - b_ * b_;
    double det = a * A00 + b_ * A01 + c_ * A02;
    double idet = 1.0 / det;
    double d0 = (A00 * rr[0] + A01 * rr[1] + A02 * rr[2]) * idet;
    double d1 = (A01 * rr[0] + A11 * rr[1] + A12 * rr[2]) * idet;
    double d2 = (A02 * rr[0] + A12 * rr[1] + A22 * rr[2]) * idet;
    float* O = out + (size_t)sample * 6;
    O[0] = q0 + 0.001f * y0;
    O[1] = q1 + 0.001f * y1;
    O[2] = q2 + 0.001f * y2;
    O[3] = y0 + 0.001f * (float)d0;
    O[4] = y1 + 0.001f * (float)d1;
    O[5] = y2 + 0.001f * (float)d2;
  }
}

// 2 samples per THREAD (4 per wave): independent chains fill each other's
// dependency stalls. buildA hoisted before MFMA to shrink live range.
// No min-occupancy launch bound (forced caps spilled in R7/R14).
__global__ __launch_bounds__(NTH) void lnn_step_kernel(Ptrs P, float* __restrict__ out) {
  __shared__ float pstage[4][32][PSTR];  // 10 KiB: 4 samples
  __shared__ float ustage[4][32][4];     // 2 KiB

  const int tid = threadIdx.x;
  const int j = tid & 31;
  const int half = tid >> 5;
  const int sA = blockIdx.x * 4 + half * 2;
  const int sB = sA + 1;

  float* prowA = &pstage[half * 2 + 0][0][0];
  float* prowB = &pstage[half * 2 + 1][0][0];
  float* urowA = &ustage[half * 2 + 0][0][0];
  float* urowB = &ustage[half * 2 + 1][0][0];
  float* pst0 = &pstage[0][0][0];
  float* pst1 = &pstage[1][0][0];
  float* pst2 = &pstage[2][0][0];
  float* pst3 = &pstage[3][0][0];
  const int l64 = tid & 63;
  const int n16 = l64 & 15;
  const int kq = l64 >> 4;

  const float* XA = P.p[I_X] + (size_t)sA * 6;
  const float* XB = P.p[I_X] + (size_t)sB * 6;
  const float qA0 = XA[0], qA1 = XA[1], qA2 = XA[2];
  const float yA0 = XA[3], yA1 = XA[4], yA2 = XA[5];
  const float qB0 = XB[0], qB1 = XB[1], qB2 = XB[2];
  const float yB0 = XB[3], yB1 = XB[4], yB2 = XB[5];

  // ---- V chains ----
  float VgA0, VgA1, VgA2, VgB0, VgB1, VgB2;
  vchainVALU(P, j, qA0, qA1, qA2, urowA, VgA0, VgA1, VgA2);
  vchainVALU(P, j, qB0, qB1, qB2, urowB, VgB0, VgB1, VgB2);

  // ---- u1, z1 ----
  float uA[4], uB[4];
  u1init(P, j, qA0, qA1, qA2, uA);
  u1init(P, j, qB0, qB1, qB2, uB);
  V16 zA = zinit(P, j, qA0, qA1, qA2, yA0, yA1, yA2);
  V16 zB = zinit(P, j, qB0, qB1, qB2, yB0, yB1, yB2);

  // ---- levels 1 and 2 ----
#pragma unroll 1
  for (int lvl = 0; lvl < 2; ++lvl) {
    const float* Wh  = P.p[lvl == 0 ? I_WH1 : I_WH2];
    const float* Wzu = P.p[lvl == 0 ? I_WZU1 : I_WZU2];
    const float* Wu  = P.p[lvl == 0 ? I_WU1 : I_WU2];
    const float* Wyu = P.p[lvl == 0 ? I_WYU1 : I_WYU2];
    const float* Wy  = P.p[lvl == 0 ? I_WY1 : I_WY2];
    const float* Wz  = P.p[lvl == 0 ? I_WZ1 : I_WZ2];
    const float* Bh  = P.p[lvl == 0 ? I_BH1 : I_BH2];
    const float* Bz  = P.p[lvl == 0 ? I_BZ1 : I_BZ2];
    const float* Bl  = P.p[lvl == 0 ? I_B1 : I_B2];
    const float* By  = P.p[lvl == 0 ? I_BY1 : I_BY2];

    V16 A2A, A2B;
    // ---- sample A: stageU -> unext/stageProd/buildA ----
    {
      *(v4f*)(urowA + j * 4) = (v4f){uA[0], uA[1], uA[2], uA[3]};
      v2f h0 = {Bh[j], 0.0f}, h1 = {0.0f, 0.0f};
      v2f s0 = {Bz[j], 0.0f}, s1 = {0.0f, 0.0f};
      v2f w0 = {Bl[j], 0.0f}, w1 = {0.0f, 0.0f};
      v2f ta0 = {By[0], 0.0f}, ta1 = {0.0f, 0.0f};
      v2f tb0 = {By[1], 0.0f}, tb1 = {0.0f, 0.0f};
      v2f tc0 = {By[2], 0.0f}, tc1 = {0.0f, 0.0f};
      stageU_all(Wh, Wzu, Wu, Wyu, j, urowA, h0, h1, s0, s1, w0, w1,
                 ta0, ta1, tb0, tb1, tc0, tc1);
      float ss = sigf(h0.x);
      uA[0] = spf(h0.x); uA[1] = ss * h0.y; uA[2] = ss * h1.x; uA[3] = ss * h1.y;
      stageProd(prowA + j * PSTR, zA, s0.x, s0.y, s1.x, s1.y, yA0, yA1, yA2);
      float wvv[4] = {w0.x, w0.y, w1.x, w1.y};
      float tav[4] = {ta0.x, ta0.y, ta1.x, ta1.y};
      float tbv[4] = {tb0.x, tb0.y, tb1.x, tb1.y};
      float tcv[4] = {tc0.x, tc0.y, tc1.x, tc1.y};
      buildA16(Wy, j, yA0, yA1, yA2, wvv, tav, tbv, tcv, A2A);
    }
    // ---- sample B ----
    {
      *(v4f*)(urowB + j * 4) = (v4f){uB[0], uB[1], uB[2], uB[3]};
      v2f h0 = {Bh[j], 0.0f}, h1 = {0.0f, 0.0f};
      v2f s0 = {Bz[j], 0.0f}, s1 = {0.0f, 0.0f};
      v2f w0 = {Bl[j], 0.0f}, w1 = {0.0f, 0.0f};
      v2f ta0 = {By[0], 0.0f}, ta1 = {0.0f, 0.0f};
      v2f tb0 = {By[1], 0.0f}, tb1 = {0.0f, 0.0f};
      v2f tc0 = {By[2], 0.0f}, tc1 = {0.0f, 0.0f};
      stageU_all(Wh, Wzu, Wu, Wyu, j, urowB, h0, h1, s0, s1, w0, w1,
                 ta0, ta1, tb0, tb1, tc0, tc1);
      float ss = sigf(h0.x);
      uB[0] = spf(h0.x); uB[1] = ss * h0.y; uB[2] = ss * h1.x; uB[3] = ss * h1.y;
      stageProd(prowB + j * PSTR, zB, s0.x, s0.y, s1.x, s1.y, yB0, yB1, yB2);
      float wvv[4] = {w0.x, w0.y, w1.x, w1.y};
      float tav[4] = {ta0.x, ta0.y, ta1.x, ta1.y};
      float tbv[4] = {tb0.x, tb0.y, tb1.x, tb1.y};
      float tcv[4] = {tc0.x, tc0.y, tc1.x, tc1.y};
      buildA16(Wy, j, yB0, yB1, yB2, wvv, tav, tbv, tcv, A2B);
    }

    // ---- MFMA: 4 sample buffers, 2 sub-passes (wave-wide) ----
    mv16pair(Wz, n16, kq, pst0, pst1);
    mv16pair(Wz, n16, kq, pst2, pst3);

    // ---- readback + spchain ----
    {
      const float* rown = prowA + j * PSTR;
      v4f r0 = *(const v4f*)(rown + 0);
      v4f r1 = *(const v4f*)(rown + 4);
      v4f r2 = *(const v4f*)(rown + 8);
      v4f r3 = *(const v4f*)(rown + 12);
      A2A.c[0] += r0.x;  A2A.c[1] += r0.y;  A2A.c[2] += r0.z;  A2A.c[3] += r0.w;
      A2A.c[4] += r1.x;  A2A.c[5] += r1.y;  A2A.c[6] += r1.z;  A2A.c[7] += r1.w;
      A2A.c[8] += r2.x;  A2A.c[9] += r2.y;  A2A.c[10] += r2.z; A2A.c[11] += r2.w;
      A2A.c[12] += r3.x; A2A.c[13] += r3.y; A2A.c[14] += r3.z; A2A.c[15] += r3.w;
    }
    zA = spchain16(A2A, yA0, yA1, yA2);
    {
      const float* rown = prowB + j * PSTR;
      v4f r0 = *(const v4f*)(rown + 0);
      v4f r1 = *(const v4f*)(rown + 4);
      v4f r2 = *(const v4f*)(rown + 8);
      v4f r3 = *(const v4f*)(rown + 12);
      A2B.c[0] += r0.x;  A2B.c[1] += r0.y;  A2B.c[2] += r0.z;  A2B.c[3] += r0.w;
      A2B.c[4] += r1.x;  A2B.c[5] += r1.y;  A2B.c[6] += r1.z;  A2B.c[7] += r1.w;
      A2B.c[8] += r2.x;  A2B.c[9] += r2.y;  A2B.c[10] += r2.z; A2B.c[11] += r2.w;
      A2B.c[12] += r3.x; A2B.c[13] += r3.y; A2B.c[14] += r3.z; A2B.c[15] += r3.w;
    }
    zB = spchain16(A2B, yB0, yB1, yB2);
  }

  // ---- level 3 + finish, per sample ----
  *(v4f*)(urowA + j * 4) = (v4f){uA[0], uA[1], uA[2], uA[3]};
  *(v4f*)(urowB + j * 4) = (v4f){uB[0], uB[1], uB[2], uB[3]};
  {
    float s3c[4], t3av[4], t3bv[4], t3cv[4], woc[4];
    level3VALU(P, j, urowA, s3c, t3av, t3bv, t3cv, woc);
    finishSample(P, j, zA, s3c, t3av, t3bv, t3cv, woc, VgA0, VgA1, VgA2,
                 qA0, qA1, qA2, yA0, yA1, yA2, out, sA);
  }
  {
    float s3c[4], t3av[4], t3bv[4], t3cv[4], woc[4];
    level3VALU(P, j, urowB, s3c, t3av, t3bv, t3cv, woc);
    finishSample(P, j, zB, s3c, t3av, t3bv, t3cv, woc, VgB0, VgB1, VgB2,
                 qB0, qB1, qB2, yB0, yB1, yB2, out, sB);
  }
}

extern "C" void kernel_launch(void* const* d_in, const int* in_sizes, int n_in,
                              void* d_out, int out_size, void* d_ws, size_t ws_size,
                              hipStream_t stream) {
  (void)in_sizes; (void)n_in; (void)d_ws; (void)ws_size; (void)out_size;
  Ptrs P;
  for (int i = 0; i < 44; ++i) P.p[i] = (const float*)d_in[i];
  float* out = (float*)d_out;
  dim3 grid(B_TOTAL / 4), block(NTH);
  hipLaunchKernelGGL(lnn_step_kernel, grid, block, 0, stream, P, out);
}

// Round 17
// 130.596 us; speedup vs baseline: 1.1875x; 1.1875x over previous
//
#include <hip/hip_runtime.h>

#define NTH 64
#define B_TOTAL 32768
#define PSTR 20  // pstage row stride in floats (80B, 16B-aligned, bank-friendly)

typedef float v2f __attribute__((ext_vector_type(2)));
typedef float v4f __attribute__((ext_vector_type(4)));
typedef double v4d __attribute__((ext_vector_type(4)));

struct Ptrs { const float* p[44]; };

// input indices
enum : int {
  I_X = 0,
  I_WH0 = 1, I_WY0 = 2, I_WYU0 = 3, I_WU0 = 4,
  I_WH1 = 5, I_WZ1 = 6, I_WZU1 = 7, I_WY1 = 8, I_WYU1 = 9, I_WU1 = 10,
  I_WH2 = 11, I_WZ2 = 12, I_WZU2 = 13, I_WY2 = 14, I_WYU2 = 15, I_WU2 = 16,
  I_WZO = 17, I_WZUO = 18, I_WYO = 19, I_WYUO = 20, I_WUO = 21,
  I_BY0 = 22, I_BH0 = 23, I_B0 = 24, I_BH1 = 25, I_BY1 = 26, I_BZ1 = 27, I_B1 = 28,
  I_BH2 = 29, I_BZ2 = 30, I_BY2 = 31, I_B2 = 32, I_BZO = 33, I_BYO = 34, I_BOUT = 35,
  I_FC1 = 36, I_FC1B = 37, I_FC2 = 38, I_FC2B = 39, I_FC3 = 40, I_FC3B = 41,
  I_FC4 = 42, I_FC4B = 43
};

// contracted jet (16): c[0]=v, c[1..3]=dy, c[4..6]=dq,
// c[7..12]=d2yy sym {00,01,02,11,12,22}, c[13..15]=cyq[a] = sum_b y_b d2/dy_a dq_b
struct V16 { float c[16]; };

__device__ __forceinline__ float spf(float x) {
  return fmaxf(x, 0.0f) + __logf(1.0f + __expf(-fabsf(x)));
}
__device__ __forceinline__ float sigf(float x) {
  return __fdividef(1.0f, 1.0f + __expf(-x));
}

__device__ __forceinline__ V16 spchain16(const V16& A, float y0, float y1, float y2) {
  V16 Z;
  float s = sigf(A.c[0]);
  float d = s * (1.0f - s);
  Z.c[0] = spf(A.c[0]);
#pragma unroll
  for (int a = 0; a < 3; ++a) Z.c[1 + a] = s * A.c[1 + a];
#pragma unroll
  for (int b = 0; b < 3; ++b) Z.c[4 + b] = s * A.c[4 + b];
  Z.c[7]  = s * A.c[7]  + d * A.c[1] * A.c[1];
  Z.c[8]  = s * A.c[8]  + d * A.c[1] * A.c[2];
  Z.c[9]  = s * A.c[9]  + d * A.c[1] * A.c[3];
  Z.c[10] = s * A.c[10] + d * A.c[2] * A.c[2];
  Z.c[11] = s * A.c[11] + d * A.c[2] * A.c[3];
  Z.c[12] = s * A.c[12] + d * A.c[3] * A.c[3];
  float ydq = y0 * A.c[4] + y1 * A.c[5] + y2 * A.c[6];
#pragma unroll
  for (int a = 0; a < 3; ++a) Z.c[13 + a] = s * A.c[13 + a] + d * A.c[1 + a] * ydq;
  return Z;
}

// P = Z * S (product rule, contracted), streamed to LDS row (stride PSTR floats)
__device__ __forceinline__ void stageProd(float* row, const V16& Z, float S0, float S1,
                                          float S2, float S3, float y0, float y1, float y2) {
  float z0 = Z.c[0];
  float ysd = y0 * S1 + y1 * S2 + y2 * S3;
  v4f w0 = {z0 * S0, S0 * Z.c[1], S0 * Z.c[2], S0 * Z.c[3]};
  v4f w1 = {z0 * S1 + S0 * Z.c[4], z0 * S2 + S0 * Z.c[5], z0 * S3 + S0 * Z.c[6], S0 * Z.c[7]};
  v4f w2 = {S0 * Z.c[8], S0 * Z.c[9], S0 * Z.c[10], S0 * Z.c[11]};
  v4f w3 = {S0 * Z.c[12], S0 * Z.c[13] + Z.c[1] * ysd, S0 * Z.c[14] + Z.c[2] * ysd,
            S0 * Z.c[15] + Z.c[3] * ysd};
  *(v4f*)(row + 0) = w0;  *(v4f*)(row + 4) = w1;
  *(v4f*)(row + 8) = w2;  *(v4f*)(row + 12) = w3;
}

// full-register product (final reduction stage only)
__device__ __forceinline__ V16 prodZS16(const V16& Z, float S0, float S1, float S2, float S3,
                                        float y0, float y1, float y2) {
  V16 P;
  const float Sq[3] = {S1, S2, S3};
  float ysd = y0 * S1 + y1 * S2 + y2 * S3;
  P.c[0] = Z.c[0] * S0;
#pragma unroll
  for (int a = 0; a < 3; ++a) P.c[1 + a] = S0 * Z.c[1 + a];
#pragma unroll
  for (int b = 0; b < 3; ++b) P.c[4 + b] = Z.c[0] * Sq[b] + S0 * Z.c[4 + b];
#pragma unroll
  for (int t = 0; t < 6; ++t) P.c[7 + t] = S0 * Z.c[7 + t];
#pragma unroll
  for (int a = 0; a < 3; ++a) P.c[13 + a] = S0 * Z.c[13 + a] + Z.c[1 + a] * ysd;
  return P;
}

// fused u-consumer: single pass over i, one urow read feeding all 12 accumulators
__device__ __forceinline__ void stageU_all(const float* __restrict__ Wh,
                                           const float* __restrict__ Wzu,
                                           const float* __restrict__ Wu,
                                           const float* __restrict__ Wyu, int j,
                                           const float* us,
                                           v2f& h0, v2f& h1, v2f& s0, v2f& s1,
                                           v2f& w0, v2f& w1,
                                           v2f& ta0, v2f& ta1, v2f& tb0, v2f& tb1,
                                           v2f& tc0, v2f& tc1) {
#pragma unroll 2
  for (int i = 0; i < 32; ++i) {
    v4f u = *(const v4f*)(us + i * 4);
    float wh = Wh[i * 32 + j], wz = Wzu[i * 32 + j], wu = Wu[i * 32 + j];
    h0 += u.xy * wh; h1 += u.zw * wh;
    s0 += u.xy * wz; s1 += u.zw * wz;
    w0 += u.xy * wu; w1 += u.zw * wu;
    float wy0 = Wyu[i * 3 + 0], wy1 = Wyu[i * 3 + 1], wy2 = Wyu[i * 3 + 2];
    ta0 += u.xy * wy0; ta1 += u.zw * wy0;
    tb0 += u.xy * wy1; tb1 += u.zw * wy1;
    tc0 += u.xy * wy2; tc1 += u.zw * wy2;
  }
}

// local (non-matvec) pre-activation terms, contracted: A = w + (y*t)@Wy
__device__ __forceinline__ void buildA16(const float* __restrict__ Wy, int j, float y0, float y1,
                                         float y2, const float wv[4], const float ta[4],
                                         const float tb[4], const float tc[4], V16& A) {
  float wy0 = Wy[j], wy1 = Wy[32 + j], wy2 = Wy[64 + j];
  A.c[0] = wv[0] + y0 * ta[0] * wy0 + y1 * tb[0] * wy1 + y2 * tc[0] * wy2;
  A.c[1] = ta[0] * wy0; A.c[2] = tb[0] * wy1; A.c[3] = tc[0] * wy2;
#pragma unroll
  for (int b = 0; b < 3; ++b)
    A.c[4 + b] = wv[1 + b] + y0 * ta[1 + b] * wy0 + y1 * tb[1 + b] * wy1 + y2 * tc[1 + b] * wy2;
#pragma unroll
  for (int t6 = 0; t6 < 6; ++t6) A.c[7 + t6] = 0.0f;
  float yta = y0 * ta[1] + y1 * ta[2] + y2 * ta[3];
  float ytb = y0 * tb[1] + y1 * tb[2] + y2 * tb[3];
  float ytc = y0 * tc[1] + y1 * tc[2] + y2 * tc[3];
  A.c[13] = yta * wy0; A.c[14] = ytb * wy1; A.c[15] = ytc * wy2;
}

// 1-wave blocks; V-chain + stageU + level-3 on VALU (serial/latency-critical --
// R12 & R14 both regressed when moved to MFMA; ILP-2 regressed in R16 via VGPR
// pressure); MFMA only for mv16 (the one matrix-shaped op). Verified plateau.
__global__ __launch_bounds__(NTH, 4) void lnn_step_kernel(Ptrs P, float* __restrict__ out) {
  // f64 16x16x4 MFMA layouts (verified R11):
  //   A[m][k]: m=lane&15 (+16/tile), k=lane>>4 (chunked)
  //   B[k][n]: n=lane&15, k=lane>>4
  //   D[m][n]: n=lane&15, m=(lane>>4) + 4*reg   (legacy x4 convention)
  __shared__ float pstage[2][32][PSTR];  // 5 KiB
  __shared__ float ustage[2][32][4];     // 1 KiB

  const int tid = threadIdx.x;
  const int j = tid & 31;
  const int half = tid >> 5;
  const int sample = blockIdx.x * 2 + half;

  float* prow = &pstage[half][0][0];
  float* urow = &ustage[half][0][0];
  float* pst0 = &pstage[0][0][0];
  float* pst1 = &pstage[1][0][0];
  const int l64 = tid & 63;
  const int n16 = l64 & 15;  // MFMA: A row m / B col n / D col
  const int kq = l64 >> 4;   // MFMA: K quarter

  const float* X = P.p[I_X] + sample * 6;
  const float q0 = X[0], q1 = X[1], q2 = X[2];
  const float y0 = X[3], y1 = X[4], y2 = X[5];

  // ---------------- V chain (VALU); keep only dV/dq ----------------
  float Vg0, Vg1, Vg2;
  {
    const float* fc1 = P.p[I_FC1];
    float f0 = fc1[j * 3], f1 = fc1[j * 3 + 1], f2 = fc1[j * 3 + 2];
    float hp = P.p[I_FC1B][j] + q0 * f0 + q1 * f1 + q2 * f2;
    float ss = sigf(hp);
    *(v4f*)(urow + j * 4) = (v4f){spf(hp), ss * f0, ss * f1, ss * f2};
    const float* fc2 = P.p[I_FC2] + j * 32;
    v2f a0 = {P.p[I_FC2B][j], 0.0f}, a1 = {0.0f, 0.0f};
#pragma unroll 2
    for (int r = 0; r < 8; ++r) {
      v4f w4 = *(const v4f*)(fc2 + r * 4);
      v4f u0 = *(const v4f*)(urow + (r * 4 + 0) * 4);
      v4f u1 = *(const v4f*)(urow + (r * 4 + 1) * 4);
      v4f u2 = *(const v4f*)(urow + (r * 4 + 2) * 4);
      v4f u3 = *(const v4f*)(urow + (r * 4 + 3) * 4);
      a0 += u0.xy * w4.x; a1 += u0.zw * w4.x;
      a0 += u1.xy * w4.y; a1 += u1.zw * w4.y;
      a0 += u2.xy * w4.z; a1 += u2.zw * w4.z;
      a0 += u3.xy * w4.w; a1 += u3.zw * w4.w;
    }
    float ss2 = sigf(a0.x);
    *(v4f*)(urow + j * 4) = (v4f){spf(a0.x), ss2 * a0.y, ss2 * a1.x, ss2 * a1.y};
    const float* fc3 = P.p[I_FC3] + j * 32;
    v2f b0 = {P.p[I_FC3B][j], 0.0f}, b1 = {0.0f, 0.0f};
#pragma unroll 2
    for (int r = 0; r < 8; ++r) {
      v4f w4 = *(const v4f*)(fc3 + r * 4);
      v4f u0 = *(const v4f*)(urow + (r * 4 + 0) * 4);
      v4f u1 = *(const v4f*)(urow + (r * 4 + 1) * 4);
      v4f u2 = *(const v4f*)(urow + (r * 4 + 2) * 4);
      v4f u3 = *(const v4f*)(urow + (r * 4 + 3) * 4);
      b0 += u0.xy * w4.x; b1 += u0.zw * w4.x;
      b0 += u1.xy * w4.y; b1 += u1.zw * w4.y;
      b0 += u2.xy * w4.z; b1 += u2.zw * w4.z;
      b0 += u3.xy * w4.w; b1 += u3.zw * w4.w;
    }
    float ss3 = sigf(b0.x);
    float f4 = P.p[I_FC4][j];
    Vg0 = ss3 * b0.y * f4; Vg1 = ss3 * b1.x * f4; Vg2 = ss3 * b1.y * f4;
  }

  // ---- t0 = q@w_yu0 + b_y0 (uniform s_loads) ----
  const float* yu0 = P.p[I_WYU0];
  float t0v[3];
#pragma unroll
  for (int k = 0; k < 3; ++k)
    t0v[k] = q0 * yu0[k] + q1 * yu0[3 + k] + q2 * yu0[6 + k] + P.p[I_BY0][k];

  // ---- u1 = sp(q@w_h0 + b_h0) ----
  float u1c[4];
  {
    const float* wh0 = P.p[I_WH0];
    float w0 = wh0[j], w1 = wh0[32 + j], w2 = wh0[64 + j];
    float h = P.p[I_BH0][j] + q0 * w0 + q1 * w1 + q2 * w2;
    float ss = sigf(h);
    u1c[0] = spf(h); u1c[1] = ss * w0; u1c[2] = ss * w1; u1c[3] = ss * w2;
  }

  // ---- z1 = sp( (y*t0)@w_y0 + q@w_u0 + b_0 ) ----
  V16 z;
  {
    const float* Wy = P.p[I_WY0];
    const float* Wu = P.p[I_WU0];
    float wy0 = Wy[j], wy1 = Wy[32 + j], wy2 = Wy[64 + j];
    float wu0 = Wu[j], wu1 = Wu[32 + j], wu2 = Wu[64 + j];
    V16 A;
    A.c[0] = P.p[I_B0][j] + (y0 * t0v[0]) * wy0 + (y1 * t0v[1]) * wy1 + (y2 * t0v[2]) * wy2 +
             q0 * wu0 + q1 * wu1 + q2 * wu2;
    A.c[1] = t0v[0] * wy0; A.c[2] = t0v[1] * wy1; A.c[3] = t0v[2] * wy2;
#pragma unroll
    for (int b = 0; b < 3; ++b) {
      float acc = (b == 0 ? wu0 : (b == 1 ? wu1 : wu2));
      acc += y0 * yu0[b * 3 + 0] * wy0 + y1 * yu0[b * 3 + 1] * wy1 + y2 * yu0[b * 3 + 2] * wy2;
      A.c[4 + b] = acc;
    }
#pragma unroll
    for (int t = 0; t < 6; ++t) A.c[7 + t] = 0.0f;
    float yty0 = y0 * yu0[0] + y1 * yu0[3] + y2 * yu0[6];
    float yty1 = y0 * yu0[1] + y1 * yu0[4] + y2 * yu0[7];
    float yty2 = y0 * yu0[2] + y1 * yu0[5] + y2 * yu0[8];
    A.c[13] = yty0 * wy0; A.c[14] = yty1 * wy1; A.c[15] = yty2 * wy2;
    z = spchain16(A, y0, y1, y2);
  }

  // ---- levels 1 and 2 (stageU on VALU, mv16 on MFMA) ----
  float unext[4];
#pragma unroll 1
  for (int lvl = 0; lvl < 2; ++lvl) {
    const float* Wh  = P.p[lvl == 0 ? I_WH1 : I_WH2];
    const float* Wzu = P.p[lvl == 0 ? I_WZU1 : I_WZU2];
    const float* Wu  = P.p[lvl == 0 ? I_WU1 : I_WU2];
    const float* Wyu = P.p[lvl == 0 ? I_WYU1 : I_WYU2];
    const float* Wy  = P.p[lvl == 0 ? I_WY1 : I_WY2];
    const float* Wz  = P.p[lvl == 0 ? I_WZ1 : I_WZ2];
    const float* Bh  = P.p[lvl == 0 ? I_BH1 : I_BH2];
    const float* Bz  = P.p[lvl == 0 ? I_BZ1 : I_BZ2];
    const float* Bl  = P.p[lvl == 0 ? I_B1 : I_B2];
    const float* By  = P.p[lvl == 0 ? I_BY1 : I_BY2];

    const float* uc = (lvl == 0) ? u1c : unext;
    *(v4f*)(urow + j * 4) = (v4f){uc[0], uc[1], uc[2], uc[3]};

    v2f h0 = {Bh[j], 0.0f}, h1 = {0.0f, 0.0f};
    v2f s0 = {Bz[j], 0.0f}, s1 = {0.0f, 0.0f};
    v2f w0 = {Bl[j], 0.0f}, w1 = {0.0f, 0.0f};
    v2f ta0 = {By[0], 0.0f}, ta1 = {0.0f, 0.0f};
    v2f tb0 = {By[1], 0.0f}, tb1 = {0.0f, 0.0f};
    v2f tc0 = {By[2], 0.0f}, tc1 = {0.0f, 0.0f};
    stageU_all(Wh, Wzu, Wu, Wyu, j, urow, h0, h1, s0, s1, w0, w1,
               ta0, ta1, tb0, tb1, tc0, tc1);
    {
      float ss = sigf(h0.x);
      unext[0] = spf(h0.x); unext[1] = ss * h0.y; unext[2] = ss * h1.x; unext[3] = ss * h1.y;
    }
    stageProd(prow + j * PSTR, z, s0.x, s0.y, s1.x, s1.y, y0, y1, y2);

    // mv16 via f64 MFMA (verified R11 layout)
    v4d a00 = {0.0, 0.0, 0.0, 0.0};
    v4d a01 = {0.0, 0.0, 0.0, 0.0};
    v4d a10 = {0.0, 0.0, 0.0, 0.0};
    v4d a11 = {0.0, 0.0, 0.0, 0.0};
#pragma unroll
    for (int c = 0; c < 8; ++c) {
      const int i = c * 4 + kq;
      double b0 = (double)pst0[i * PSTR + n16];
      double b1 = (double)pst1[i * PSTR + n16];
      double wlo = (double)fmaxf(Wz[i * 32 + n16], 0.0f);
      double whi = (double)fmaxf(Wz[i * 32 + 16 + n16], 0.0f);
      a00 = __builtin_amdgcn_mfma_f64_16x16x4f64(wlo, b0, a00, 0, 0, 0);
      a01 = __builtin_amdgcn_mfma_f64_16x16x4f64(whi, b0, a01, 0, 0, 0);
      a10 = __builtin_amdgcn_mfma_f64_16x16x4f64(wlo, b1, a10, 0, 0, 0);
      a11 = __builtin_amdgcn_mfma_f64_16x16x4f64(whi, b1, a11, 0, 0, 0);
    }
#pragma unroll
    for (int r = 0; r < 4; ++r) {
      pst0[(kq + 4 * r) * PSTR + n16]        = (float)a00[r];
      pst0[(16 + kq + 4 * r) * PSTR + n16]   = (float)a01[r];
      pst1[(kq + 4 * r) * PSTR + n16]        = (float)a10[r];
      pst1[(16 + kq + 4 * r) * PSTR + n16]   = (float)a11[r];
    }

    float wvv[4] = {w0.x, w0.y, w1.x, w1.y};
    float tav[4] = {ta0.x, ta0.y, ta1.x, ta1.y};
    float tbv[4] = {tb0.x, tb0.y, tb1.x, tb1.y};
    float tcv[4] = {tc0.x, tc0.y, tc1.x, tc1.y};
    V16 A2;
    buildA16(Wy, j, y0, y1, y2, wvv, tav, tbv, tcv, A2);

    {
      const float* rown = prow + j * PSTR;
      v4f r0 = *(const v4f*)(rown + 0);
      v4f r1 = *(const v4f*)(rown + 4);
      v4f r2 = *(const v4f*)(rown + 8);
      v4f r3 = *(const v4f*)(rown + 12);
      A2.c[0] += r0.x;  A2.c[1] += r0.y;  A2.c[2] += r0.z;  A2.c[3] += r0.w;
      A2.c[4] += r1.x;  A2.c[5] += r1.y;  A2.c[6] += r1.z;  A2.c[7] += r1.w;
      A2.c[8] += r2.x;  A2.c[9] += r2.y;  A2.c[10] += r2.z; A2.c[11] += r2.w;
      A2.c[12] += r3.x; A2.c[13] += r3.y; A2.c[14] += r3.z; A2.c[15] += r3.w;
    }
    z = spchain16(A2, y0, y1, y2);
  }

  // ---- level 3 (output-stage pre-terms), fused single pass (VALU) ----
  *(v4f*)(urow + j * 4) = (v4f){unext[0], unext[1], unext[2], unext[3]};
  v2f s30 = {P.p[I_BZO][j], 0.0f}, s31 = {0.0f, 0.0f};
  v2f wo0 = {0.0f, 0.0f}, wo1 = {0.0f, 0.0f};
  v2f t3a0 = {P.p[I_BYO][0], 0.0f}, t3a1 = {0.0f, 0.0f};
  v2f t3b0 = {P.p[I_BYO][1], 0.0f}, t3b1 = {0.0f, 0.0f};
  v2f t3c0 = {P.p[I_BYO][2], 0.0f}, t3c1 = {0.0f, 0.0f};
  {
    const float* Wzuo = P.p[I_WZUO];
    const float* Wuo = P.p[I_WUO];
    const float* Wyuo = P.p[I_WYUO];
#pragma unroll 2
    for (int i = 0; i < 32; ++i) {
      v4f u = *(const v4f*)(urow + i * 4);
      float wz = Wzuo[i * 32 + j];
      s30 += u.xy * wz; s31 += u.zw * wz;
      float wu = Wuo[i];  // uniform -> s_load
      wo0 += u.xy * wu; wo1 += u.zw * wu;
      float wy0 = Wyuo[i * 3], wy1 = Wyuo[i * 3 + 1], wy2 = Wyuo[i * 3 + 2];
      t3a0 += u.xy * wy0; t3a1 += u.zw * wy0;
      t3b0 += u.xy * wy1; t3b1 += u.zw * wy1;
      t3c0 += u.xy * wy2; t3c1 += u.zw * wy2;
    }
  }
  const float woc[4] = {wo0.x, wo0.y, wo1.x, wo1.y};
  const float t3av[4] = {t3a0.x, t3a0.y, t3a1.x, t3a1.y};
  const float t3bv[4] = {t3b0.x, t3b0.y, t3b1.x, t3b1.y};
  const float t3cv[4] = {t3c0.x, t3c0.y, t3c1.x, t3c1.y};

  // ---- p3 = z3*s3, reduce 19 comps over 32 lanes ----
  float red[19];
  {
    V16 p3 = prodZS16(z, s30.x, s30.y, s31.x, s31.y, y0, y1, y2);
    float wz = fmaxf(P.p[I_WZO][j], 0.0f);  // relu(w_z_out)
#pragma unroll
    for (int k = 0; k < 16; ++k) red[k] = p3.c[k] * wz;
    red[16] = Vg0; red[17] = Vg1; red[18] = Vg2;
  }
#pragma unroll
  for (int m = 16; m >= 1; m >>= 1) {
#pragma unroll
    for (int k = 0; k < 19; ++k) red[k] += __shfl_xor(red[k], m, 32);
  }

  if (j == 0) {
    const float* Wyo = P.p[I_WYO];
    const float wyo0 = Wyo[0], wyo1 = Wyo[1], wyo2 = Wyo[2];
    float Av = red[0] + woc[0] + P.p[I_BOUT][0] + y0 * t3av[0] * wyo0 +
               y1 * t3bv[0] * wyo1 + y2 * t3cv[0] * wyo2;
    float Agy[3];
    Agy[0] = red[1] + t3av[0] * wyo0;
    Agy[1] = red[2] + t3bv[0] * wyo1;
    Agy[2] = red[3] + t3cv[0] * wyo2;
    float Agq[3];
#pragma unroll
    for (int b = 0; b < 3; ++b)
      Agq[b] = red[4 + b] + woc[1 + b] + y0 * t3av[1 + b] * wyo0 +
               y1 * t3bv[1 + b] * wyo1 + y2 * t3cv[1 + b] * wyo2;
    float ycq[3];
    ycq[0] = red[13] + (y0 * t3av[1] + y1 * t3av[2] + y2 * t3av[3]) * wyo0;
    ycq[1] = red[14] + (y0 * t3bv[1] + y1 * t3bv[2] + y2 * t3bv[3]) * wyo1;
    ycq[2] = red[15] + (y0 * t3cv[1] + y1 * t3cv[2] + y2 * t3cv[3]) * wyo2;
    float s = sigf(Av), d = s * (1.0f - s);

    double Mm[3][3];
    const int pa[6] = {0, 0, 0, 1, 1, 2}, pb[6] = {0, 1, 2, 1, 2, 2};
#pragma unroll
    for (int t = 0; t < 6; ++t) {
      double m = (double)s * (double)red[7 + t] +
                 (double)d * (double)Agy[pa[t]] * (double)Agy[pb[t]];
      Mm[pa[t]][pb[t]] = m; Mm[pb[t]][pa[t]] = m;
    }
    double yAgq = (double)y0 * (double)Agq[0] + (double)y1 * (double)Agq[1] +
                  (double)y2 * (double)Agq[2];
    double rr[3];
#pragma unroll
    for (int a = 0; a < 3; ++a) {
      double g = (double)s * (double)Agq[a] - (double)red[16 + a];
      double Cy = (double)s * (double)ycq[a] + (double)d * (double)Agy[a] * yAgq;
      rr[a] = g - Cy;
    }
    double a = Mm[0][0], b_ = Mm[0][1], c_ = Mm[0][2], dd = Mm[1][1], e = Mm[1][2], f = Mm[2][2];
    double A00 = dd * f - e * e, A01 = c_ * e - b_ * f, A02 = b_ * e - c_ * dd;
    double A11 = a * f - c_ * c_, A12 = b_ * c_ - a * e, A22 = a * dd - b_ * b_;
    double det = a * A00 + b_ * A01 + c_ * A02;
    double idet = 1.0 / det;
    double d0 = (A00 * rr[0] + A01 * rr[1] + A02 * rr[2]) * idet;
    double d1 = (A01 * rr[0] + A11 * rr[1] + A12 * rr[2]) * idet;
    double d2 = (A02 * rr[0] + A12 * rr[1] + A22 * rr[2]) * idet;

    float* O = out + (size_t)sample * 6;
    O[0] = q0 + 0.001f * y0;
    O[1] = q1 + 0.001f * y1;
    O[2] = q2 + 0.001f * y2;
    O[3] = y0 + 0.001f * (float)d0;
    O[4] = y1 + 0.001f * (float)d1;
    O[5] = y2 + 0.001f * (float)d2;
  }
}

extern "C" void kernel_launch(void* const* d_in, const int* in_sizes, int n_in,
                              void* d_out, int out_size, void* d_ws, size_t ws_size,
                              hipStream_t stream) {
  (void)in_sizes; (void)n_in; (void)d_ws; (void)ws_size; (void)out_size;
  Ptrs P;
  for (int i = 0; i < 44; ++i) P.p[i] = (const float*)d_in[i];
  float* out = (float*)d_out;
  dim3 grid(B_TOTAL / 2), block(NTH);
  hipLaunchKernelGGL(lnn_step_kernel, grid, block, 0, stream, P, out);
}